// Round 11
// baseline (473.772 us; speedup 1.0000x reference)
//
#include <hip/hip_runtime.h>
#include <hip/hip_bf16.h>

// Problem: B=128, T=256, D=1024.  TOK = B*T = 32768.
// keys = x@Wk.T+bk ; queries = x@Wq.T+bq ; values = x@Wv.T+bv
// S = tril(Q K^T / 32) ; P = softmax(S) ; out = P V   (fp32 out)

typedef __attribute__((ext_vector_type(4))) float f32x4;
typedef __attribute__((ext_vector_type(8))) short s16x8;
typedef unsigned short u16;

__device__ inline u16 f2bf(float f) {
    union { __hip_bfloat16 h; u16 u; } c;
    c.h = __float2bfloat16(f);
    return c.u;
}

// async global->LDS DMA, 16B/lane, dest = wave-uniform base + lane*16
__device__ __forceinline__ void stage16(const void* g, void* l) {
    __builtin_amdgcn_global_load_lds((const __attribute__((address_space(1))) void*)g,
                                     (__attribute__((address_space(3))) void*)l, 16, 0, 0);
}

#define MFMA(a_, b_, c_) (c_) = __builtin_amdgcn_mfma_f32_16x16x32_bf16((a_), (b_), (c_), 0, 0, 0)

// ---------------- fp32 -> bf16 convert ----------------
__global__ __launch_bounds__(256) void cvt_f32_bf16(const float* __restrict__ in,
                                                    u16* __restrict__ out, int n4) {
    int stride = gridDim.x * blockDim.x;
    for (int i = blockIdx.x * blockDim.x + threadIdx.x; i < n4; i += stride) {
        float4 v = reinterpret_cast<const float4*>(in)[i];
        ushort4 o = make_ushort4(f2bf(v.x), f2bf(v.y), f2bf(v.z), f2bf(v.w));
        reinterpret_cast<ushort4*>(out)[i] = o;
    }
}

// ====== 128x256-tile QKV GEMM @ 2 blocks/CU, PREFETCH DISTANCE 2 ======
// Only change vs R9 (passed, 302us, MfmaUtil 30%): prefetch depth 1->2.
// R9 step-arithmetic: wall 3776 cyc/step vs ~1865 cyc pipe work; the gap ~=
// one DMA round-trip, because STG(u+1) at step-u start + vmcnt(0) at step-u
// end gives the DMA only ONE step to land -> every step pays the latency
// tail, and both resident blocks stall on the same cadence (correlated).
// Now: 3 bufs x 24 KiB (72 KiB/block -> still 2 blocks/CU), STG(u+2) each
// step, end-of-step vmcnt(3) (counted, never 0 until drain).
//   RAW: tile u's 3 DMAs retired by vmcnt(3) at end of u-1 (outstanding
//        there = t_u(3) + t_{u+1}(3) = 6 -> waits t_u).  DMA gets ~2 steps.
//   WAR: STG(u+2) overwrites buf[(u-1)%3]; step u-1's ds_reads drained
//        before its closing barrier (lgkmcnt precedes MFMA consumption).
//   Drain: u=30 vmcnt(0) (only t31's 3 outstanding -> vmcnt(3) would no-op).
// Bank swizzle: phys slot = logical ^ ((row>>1)&3) (exact 2-way = free);
// DMA dest linear, global SOURCE pre-swizzled with the same involution.
__global__ __launch_bounds__(512, 4) void qkv128(const u16* __restrict__ X, const u16* __restrict__ W3,
                                                 const float* __restrict__ biasK,
                                                 const float* __restrict__ biasQ,
                                                 const float* __restrict__ biasV,
                                                 u16* __restrict__ Kb, u16* __restrict__ Qb,
                                                 u16* __restrict__ Vt) {
    __shared__ char lds[73728];   // 3 bufs x 24576: A [128][32] @+0, B [256][32] @+8192

    const int bid = blockIdx.x;
    const int swz = (bid & 7) * 384 + (bid >> 3);   // 3072 % 8 == 0: bijective XCD swizzle
    const int mt = swz / 12, nt2 = swz % 12;        // 256 m-tiles x (3 mats x 4 col-tiles)
    const int nmat = nt2 >> 2, ncol = nt2 & 3;
    const u16* Asrc = X + (size_t)mt * 128 * 1024;
    const u16* Bsrc = W3 + (size_t)nmat * 1048576 + (size_t)ncol * 256 * 1024;

    const int tid  = threadIdx.x;
    const int lane = tid & 63, w = tid >> 6;
    const int wr = w >> 2, wc = w & 3;              // 2M x 4N waves, per-wave 64x64
    const int l15 = lane & 15, l16 = lane >> 4;

    // swizzled ds_read offset: row l15 within a 16-row frag, k-slot l16
    const int rdoff = l15 * 64 + (((l16 ^ ((l15 >> 1) & 3)) & 3) << 4);
    const int aoff = wr * 4096 + rdoff;             // + fm*1024
    const int boff = 8192 + wc * 4096 + rdoff;      // + fn*1024

    // staging: thread t -> row t>>2, linear slot t&3; src col pre-swizzled
    const int srow = tid >> 2, sslot = tid & 3;
    const int scol = (sslot ^ ((srow >> 1) & 3)) * 8;       // elements
    const u16* asrcp  = Asrc + (size_t)srow * 1024 + scol;
    const u16* bsrcp0 = Bsrc + (size_t)srow * 1024 + scol;          // B rows 0-127
    const u16* bsrcp1 = Bsrc + (size_t)(srow + 128) * 1024 + scol;  // B rows 128-255

    f32x4 acc[4][4] = {};

    // one K-tile (BK=32) = 24 KB = 3 DMA per thread-group round
#define STG(u_) do {                                                              \
        char* bb_ = lds + (((u_) % 3) * 24576) + w * 1024;                        \
        const size_t ko_ = (size_t)(u_) * 32;                                     \
        stage16(asrcp  + ko_, bb_);                                               \
        stage16(bsrcp0 + ko_, bb_ + 8192);                                        \
        stage16(bsrcp1 + ko_, bb_ + 16384);                                       \
    } while (0)

    // prologue: t0,t1 in flight; retire t0 (vmcnt(3)); t1 lands during step 0
    STG(0); STG(1);
    asm volatile("s_waitcnt vmcnt(3)" ::: "memory");
    __builtin_amdgcn_s_barrier();

    for (int u = 0; u < 32; ++u) {
        if (u < 30) STG(u + 2);
        const char* bp = lds + (u % 3) * 24576;
        s16x8 a[4], b[4];
#pragma unroll
        for (int fm = 0; fm < 4; ++fm) a[fm] = *(const s16x8*)(bp + aoff + fm * 1024);
#pragma unroll
        for (int fn = 0; fn < 4; ++fn) b[fn] = *(const s16x8*)(bp + boff + fn * 1024);
        __builtin_amdgcn_s_setprio(1);
#pragma unroll
        for (int fm = 0; fm < 4; ++fm)
#pragma unroll
            for (int fn = 0; fn < 4; ++fn)
                MFMA(a[fm], b[fn], acc[fm][fn]);
        __builtin_amdgcn_s_setprio(0);
        if (u < 30) asm volatile("s_waitcnt vmcnt(3)" ::: "memory");
        else        asm volatile("s_waitcnt vmcnt(0)" ::: "memory");
        __builtin_amdgcn_s_barrier();
    }
#undef STG

    // ---- epilogue: bias + convert + store ----
    const float* bias = (nmat == 0) ? biasK : (nmat == 1) ? biasQ : biasV;
    u16* outKQ = (nmat == 0) ? Kb : Qb;
    const int r0 = l16 << 2;
#pragma unroll
    for (int m = 0; m < 4; ++m) {
#pragma unroll
        for (int n = 0; n < 4; ++n) {
            const int col = ncol * 256 + wc * 64 + n * 16 + l15;
            const float bvv = bias[col];
            const int rbase = mt * 128 + wr * 64 + m * 16 + r0;
#pragma unroll
            for (int j = 0; j < 4; ++j) {
                const int row = rbase + j;
                const u16 hb = f2bf(acc[m][n][j] + bvv);
                if (nmat == 2) {
                    const int b2 = row >> 8, tt2 = row & 255;
                    Vt[(size_t)b2 * 262144 + (size_t)col * 256 + tt2] = hb;
                } else {
                    outKQ[(size_t)row * 1024 + col] = hb;
                }
            }
        }
    }
}

// ====== FUSED scores + softmax: P = softmax(tril(Q K^T / 32)) as bf16 ======
// grid = 128 batches x 2 row-halves (ti).  Block owns COMPLETE causal rows:
// ti=0 -> rows 0-127, cols 0-127; ti=1 -> rows 128-255, cols 0-255.
// Eliminates the S f32 round-trip (~128 MB HBM) and the softmax_p dispatch.
// 4 waves (2Mx2N); acc[nt][4][4] per wave (nt = col 128-tile, <=2).
// Softmax: in-reg scale+mask -> wave-local row max (shfl over 16-lane group)
// -> cross-wave combine via redM[2][128] -> exp+sum same path -> P=e/sum.
__global__ __launch_bounds__(256) void scores_sm(const u16* __restrict__ Qb,
                                                 const u16* __restrict__ Kb,
                                                 u16* __restrict__ P) {
    __shared__ u16 As[128 * 64];
    __shared__ u16 Bs[256 * 64];
    __shared__ float redM[2][128];
    __shared__ float redS[2][128];

    const int bid = blockIdx.x;
    const int b = bid >> 1, ti = bid & 1;
    const int nB = 1 + ti;                              // col 128-tiles
    const u16* Ap = Qb + ((size_t)b * 256 + (size_t)ti * 128) * 1024;
    const u16* Bp = Kb + (size_t)b * 256 * 1024;

    const int tid  = threadIdx.x;
    const int lane = tid & 63;
    const int wr   = (tid >> 7) & 1;
    const int wc   = (tid >> 6) & 1;
    const int sr   = tid >> 3;
    const int sc   = (tid & 7) << 3;

    f32x4 acc[2][4][4] = {};

    for (int k0 = 0; k0 < 1024; k0 += 64) {
#pragma unroll
        for (int it = 0; it < 4; ++it) {
            int r = it * 32 + sr;
            *reinterpret_cast<s16x8*>(&As[r * 64 + sc]) =
                *reinterpret_cast<const s16x8*>(&Ap[(size_t)r * 1024 + k0 + sc]);
        }
#pragma unroll
        for (int it = 0; it < 8; ++it) {
            if (it < 4 * nB) {
                int r = it * 32 + sr;
                *reinterpret_cast<s16x8*>(&Bs[r * 64 + sc]) =
                    *reinterpret_cast<const s16x8*>(&Bp[(size_t)r * 1024 + k0 + sc]);
            }
        }
        __syncthreads();
#pragma unroll
        for (int kk = 0; kk < 64; kk += 32) {
            const int kcol = kk + (lane >> 4) * 8;
            s16x8 a[4], bb[2][4];
#pragma unroll
            for (int m = 0; m < 4; ++m)
                a[m] = *reinterpret_cast<const s16x8*>(&As[(wr * 64 + m * 16 + (lane & 15)) * 64 + kcol]);
#pragma unroll
            for (int nt = 0; nt < 2; ++nt)
                if (nt < nB)
#pragma unroll
                    for (int n = 0; n < 4; ++n)
                        bb[nt][n] = *reinterpret_cast<const s16x8*>(&Bs[(nt * 128 + wc * 64 + n * 16 + (lane & 15)) * 64 + kcol]);
#pragma unroll
            for (int nt = 0; nt < 2; ++nt)
                if (nt < nB)
#pragma unroll
                    for (int m = 0; m < 4; ++m)
#pragma unroll
                        for (int n = 0; n < 4; ++n)
                            MFMA(a[m], bb[nt][n], acc[nt][m][n]);
        }
        __syncthreads();
    }

    // ---- fused softmax ----
    const int r0 = (lane >> 4) << 2;
    const int c0 = lane & 15;
    const float scale = 0.03125f;
    const float NEG = -__builtin_inff();

    // phase 1: scale+mask in place; wave-local row max; publish per-wave partial
#pragma unroll
    for (int m = 0; m < 4; ++m) {
#pragma unroll
        for (int j = 0; j < 4; ++j) {
            const int rr = wr * 64 + m * 16 + r0 + j;    // row within 128-row tile
            const int t_ = ti * 128 + rr;
            float mx = NEG;
#pragma unroll
            for (int nt = 0; nt < 2; ++nt)
                if (nt < nB)
#pragma unroll
                    for (int n = 0; n < 4; ++n) {
                        const int s_ = nt * 128 + wc * 64 + n * 16 + c0;
                        float v = acc[nt][m][n][j] * scale;
                        v = (s_ <= t_) ? v : NEG;
                        acc[nt][m][n][j] = v;
                        mx = fmaxf(mx, v);
                    }
#pragma unroll
            for (int off = 1; off < 16; off <<= 1) mx = fmaxf(mx, __shfl_xor(mx, off, 64));
            if (c0 == 0) redM[wc][rr] = mx;
        }
    }
    __syncthreads();

    // phase 2: exp (store in place) + row sum; publish per-wave partial
#pragma unroll
    for (int m = 0; m < 4; ++m) {
#pragma unroll
        for (int j = 0; j < 4; ++j) {
            const int rr = wr * 64 + m * 16 + r0 + j;
            const float MX = fmaxf(redM[0][rr], redM[1][rr]);
            float s = 0.f;
#pragma unroll
            for (int nt = 0; nt < 2; ++nt)
                if (nt < nB)
#pragma unroll
                    for (int n = 0; n < 4; ++n) {
                        float e = __expf(acc[nt][m][n][j] - MX);   // exp(-inf)=0 for masked
                        acc[nt][m][n][j] = e;
                        s += e;
                    }
#pragma unroll
            for (int off = 1; off < 16; off <<= 1) s += __shfl_xor(s, off, 64);
            if (c0 == 0) redS[wc][rr] = s;
        }
    }
    __syncthreads();

    // phase 3: normalize + store bf16
#pragma unroll
    for (int m = 0; m < 4; ++m) {
#pragma unroll
        for (int j = 0; j < 4; ++j) {
            const int rr = wr * 64 + m * 16 + r0 + j;
            const int t_ = ti * 128 + rr;
            const float inv = 1.0f / (redS[0][rr] + redS[1][rr]);
            u16* Pr = P + (size_t)b * 65536 + (size_t)t_ * 256;
#pragma unroll
            for (int nt = 0; nt < 2; ++nt)
                if (nt < nB)
#pragma unroll
                    for (int n = 0; n < 4; ++n) {
                        const int s_ = nt * 128 + wc * 64 + n * 16 + c0;
                        Pr[s_] = f2bf(acc[nt][m][n][j] * inv);
                    }
        }
    }
}

// ---------------- R1 reg-staged 128x128 mainloop (pv) ----------------
__device__ inline void gemm_mainloop(const u16* __restrict__ Ap, const u16* __restrict__ Bp,
                                     int lda, int ldb, int kLen,
                                     u16* As, u16* Bs, f32x4 (&acc)[4][4]) {
    const int tid  = threadIdx.x;
    const int lane = tid & 63;
    const int wr   = (tid >> 7) & 1;
    const int wc   = (tid >> 6) & 1;
    const int sr   = tid >> 3;
    const int sc   = (tid & 7) << 3;

    for (int k0 = 0; k0 < kLen; k0 += 64) {
#pragma unroll
        for (int it = 0; it < 4; ++it) {
            int r = it * 32 + sr;
            *reinterpret_cast<s16x8*>(&As[r * 64 + sc]) =
                *reinterpret_cast<const s16x8*>(&Ap[(size_t)r * lda + k0 + sc]);
            *reinterpret_cast<s16x8*>(&Bs[r * 64 + sc]) =
                *reinterpret_cast<const s16x8*>(&Bp[(size_t)r * ldb + k0 + sc]);
        }
        __syncthreads();
#pragma unroll
        for (int kk = 0; kk < 64; kk += 32) {
            const int kcol = kk + (lane >> 4) * 8;
            s16x8 a[4], bfr[4];
#pragma unroll
            for (int m = 0; m < 4; ++m)
                a[m] = *reinterpret_cast<const s16x8*>(&As[(wr * 64 + m * 16 + (lane & 15)) * 64 + kcol]);
#pragma unroll
            for (int n = 0; n < 4; ++n)
                bfr[n] = *reinterpret_cast<const s16x8*>(&Bs[(wc * 64 + n * 16 + (lane & 15)) * 64 + kcol]);
#pragma unroll
            for (int m = 0; m < 4; ++m)
#pragma unroll
                for (int n = 0; n < 4; ++n)
                    acc[m][n] = __builtin_amdgcn_mfma_f32_16x16x32_bf16(a[m], bfr[n], acc[m][n], 0, 0, 0);
        }
        __syncthreads();
    }
}

// ---------------- PV: out = P @ V  (Vt is [b][d][t] so NT) ----------------
__global__ __launch_bounds__(256) void pv_gemm(const u16* __restrict__ P, const u16* __restrict__ Vt,
                                               float* __restrict__ O) {
    __shared__ u16 As[128 * 64];
    __shared__ u16 Bs[128 * 64];
    const int bid = blockIdx.x;
    const int b   = bid >> 4;
    const int r   = bid & 15;
    const int mt  = r >> 3;
    const int ntl = r & 7;
    const u16* Ap = P + (size_t)b * 65536 + (size_t)mt * 128 * 256;
    const u16* Bp = Vt + (size_t)b * 262144 + (size_t)ntl * 128 * 256;
    const int kmax = (mt + 1) * 128;

    f32x4 acc[4][4] = {};
    gemm_mainloop(Ap, Bp, 256, 256, kmax, As, Bs, acc);

    const int tid  = threadIdx.x;
    const int lane = tid & 63;
    const int wr   = (tid >> 7) & 1;
    const int wc   = (tid >> 6) & 1;
    const int r0 = (lane >> 4) << 2;
    const int c0 = lane & 15;
#pragma unroll
    for (int m = 0; m < 4; ++m) {
#pragma unroll
        for (int n = 0; n < 4; ++n) {
            const int d = ntl * 128 + wc * 64 + n * 16 + c0;
#pragma unroll
            for (int j = 0; j < 4; ++j) {
                const int t = mt * 128 + wr * 64 + m * 16 + r0 + j;
                O[((size_t)b * 256 + t) * 1024 + d] = acc[m][n][j];
            }
        }
    }
}

// ---------------- launcher ----------------
extern "C" void kernel_launch(void* const* d_in, const int* in_sizes, int n_in,
                              void* d_out, int out_size, void* d_ws, size_t ws_size,
                              hipStream_t stream) {
    (void)in_sizes; (void)n_in; (void)out_size; (void)ws_size;
    const float* x  = (const float*)d_in[0];
    const float* Wk = (const float*)d_in[1];
    const float* bk = (const float*)d_in[2];
    const float* Wq = (const float*)d_in[3];
    const float* bq = (const float*)d_in[4];
    const float* Wv = (const float*)d_in[5];
    const float* bv = (const float*)d_in[6];
    float* out = (float*)d_out;
    char* ws = (char*)d_ws;

    // ws layout (bytes):
    //   [0,            67108864)  xb  bf16 x [32768][1024]  (dead after qkv)
    //   [33554432,     50331648)  P   bf16 [128][256][256]  (overlays dead xb)
    //   [67108864,     73400320)  Wb  bf16 Wk|Wq|Wv
    //   [73400320,    140509184)  Kb ; [140509184, 207618048) Qb
    //   [207618048,   274726912)  Vt  bf16 values^T [128][1024][256]
    u16*   xb = (u16*)(ws + 0);
    u16*   Wb = (u16*)(ws + 67108864);
    u16*   Kb = (u16*)(ws + 73400320);
    u16*   Qb = (u16*)(ws + 140509184);
    u16*   Vt = (u16*)(ws + 207618048);
    u16*   P  = (u16*)(ws + 33554432);

    cvt_f32_bf16<<<2048, 256, 0, stream>>>(x, xb, 33554432 / 4);
    cvt_f32_bf16<<<512, 256, 0, stream>>>(Wk, Wb, 1048576 / 4);
    cvt_f32_bf16<<<512, 256, 0, stream>>>(Wq, Wb + 1048576, 1048576 / 4);
    cvt_f32_bf16<<<512, 256, 0, stream>>>(Wv, Wb + 2097152, 1048576 / 4);
    qkv128<<<3072, 512, 0, stream>>>(xb, Wb, bk, bq, bv, Kb, Qb, Vt);
    scores_sm<<<256, 256, 0, stream>>>(Qb, Kb, P);
    pv_gemm<<<2048, 256, 0, stream>>>(P, Vt, out);
}

// Round 12
// 412.688 us; speedup vs baseline: 1.1480x; 1.1480x over previous
//
#include <hip/hip_runtime.h>
#include <hip/hip_bf16.h>

// Problem: B=128, T=256, D=1024.  TOK = B*T = 32768.
// keys = x@Wk.T+bk ; queries = x@Wq.T+bq ; values = x@Wv.T+bv
// S = tril(Q K^T / 32) ; P = softmax(S) ; out = P V   (fp32 out)

typedef __attribute__((ext_vector_type(4))) float f32x4;
typedef __attribute__((ext_vector_type(8))) short s16x8;
typedef unsigned short u16;

__device__ inline u16 f2bf(float f) {
    union { __hip_bfloat16 h; u16 u; } c;
    c.h = __float2bfloat16(f);
    return c.u;
}

// async global->LDS DMA, 16B/lane, dest = wave-uniform base + lane*16
__device__ __forceinline__ void stage16(const void* g, void* l) {
    __builtin_amdgcn_global_load_lds((const __attribute__((address_space(1))) void*)g,
                                     (__attribute__((address_space(3))) void*)l, 16, 0, 0);
}

#define MFMA(a_, b_, c_) (c_) = __builtin_amdgcn_mfma_f32_16x16x32_bf16((a_), (b_), (c_), 0, 0, 0)

// ---------------- fp32 -> bf16 convert ----------------
__global__ __launch_bounds__(256) void cvt_f32_bf16(const float* __restrict__ in,
                                                    u16* __restrict__ out, int n4) {
    int stride = gridDim.x * blockDim.x;
    for (int i = blockIdx.x * blockDim.x + threadIdx.x; i < n4; i += stride) {
        float4 v = reinterpret_cast<const float4*>(in)[i];
        ushort4 o = make_ushort4(f2bf(v.x), f2bf(v.y), f2bf(v.z), f2bf(v.w));
        reinterpret_cast<ushort4*>(out)[i] = o;
    }
}

// ======== R7 qkv256 VERBATIM (best measured: ~300us) ========
__global__ __launch_bounds__(512, 2) void qkv256(const u16* __restrict__ X, const u16* __restrict__ W3,
                                                 const float* __restrict__ biasK,
                                                 const float* __restrict__ biasQ,
                                                 const float* __restrict__ biasV,
                                                 u16* __restrict__ Kb, u16* __restrict__ Qb,
                                                 u16* __restrict__ Vt) {
    extern __shared__ char lds[];  // 131072 B = 4 bufs * 32768

    const int bid = blockIdx.x;
    const int swz = (bid & 7) * 192 + (bid >> 3);  // 1536 % 8 == 0: bijective XCD swizzle
    const int mt = swz / 12, nt2 = swz % 12;
    const int nmat = nt2 >> 2, ncol = nt2 & 3;
    const u16* Asrc = X + (size_t)mt * 256 * 1024;
    const u16* Bsrc = W3 + (size_t)nmat * 1048576 + (size_t)ncol * 256 * 1024;

    const int tid  = threadIdx.x;
    const int lane = tid & 63, w = tid >> 6;
    const int wr = w >> 2, wc = w & 3;
    const int l15 = lane & 15, l16 = lane >> 4;

    const int lds_ro = l15 * 64 + ((l16 ^ ((l15 >> 1) & 3)) << 4);
    const int aoff = wr * 128 * 64 + lds_ro;
    const int boff = 16384 + wc * 64 * 64 + lds_ro;

    const int isB = w >> 2;
    const u16* dsrc = isB ? Bsrc : Asrc;
    const int drow  = (w & 3) * 64 + (lane >> 2);
    const int dslot = ((lane & 3) ^ ((lane >> 3) & 3)) * 8;
    const u16* dptr0 = dsrc + (size_t)drow * 1024 + dslot;
    const int dlds = isB * 16384 + (w & 3) * 4096;

#define STAGE(u_) do {                                                            \
        char* bb_ = lds + (((u_) & 3) * 32768) + dlds;                            \
        const u16* gp_ = dptr0 + (size_t)(u_) * 32;                               \
        stage16(gp_,             bb_);                                            \
        stage16(gp_ + 16 * 1024, bb_ + 1024);                                     \
        stage16(gp_ + 32 * 1024, bb_ + 2048);                                     \
        stage16(gp_ + 48 * 1024, bb_ + 3072);                                     \
    } while (0)

#define RDA(d_, bp_, fm_) d_[fm_] = *(const s16x8*)((bp_) + aoff + (fm_) * 1024)
#define RDB(d_, bp_, fn_) d_[fn_] = *(const s16x8*)((bp_) + boff + (fn_) * 1024)

#define MM4(fm_, a_, b_) do {                                                     \
        MFMA(a_[fm_], b_[0], acc[fm_][0]);                                        \
        MFMA(a_[fm_], b_[1], acc[fm_][1]);                                        \
        MFMA(a_[fm_], b_[2], acc[fm_][2]);                                        \
        MFMA(a_[fm_], b_[3], acc[fm_][3]);                                        \
    } while (0)

#define STEP(u_, AR_, BR_, AM_, BM_) do {                                         \
        if ((u_) + 2 <= 31) STAGE((u_) + 2);                                      \
        const char* bp_ = lds + (((u_) & 3) * 32768);                             \
        RDA(AR_, bp_, 0); RDA(AR_, bp_, 1); RDA(AR_, bp_, 2);                     \
        MM4(0, AM_, BM_); MM4(1, AM_, BM_);                                       \
        RDA(AR_, bp_, 3); RDA(AR_, bp_, 4); RDA(AR_, bp_, 5);                     \
        MM4(2, AM_, BM_); MM4(3, AM_, BM_);                                       \
        RDA(AR_, bp_, 6); RDA(AR_, bp_, 7); RDB(BR_, bp_, 0);                     \
        MM4(4, AM_, BM_); MM4(5, AM_, BM_);                                       \
        RDB(BR_, bp_, 1); RDB(BR_, bp_, 2); RDB(BR_, bp_, 3);                     \
        MM4(6, AM_, BM_); MM4(7, AM_, BM_);                                       \
        if ((u_) <= 29) asm volatile("s_waitcnt vmcnt(4)" ::: "memory");          \
        else            asm volatile("s_waitcnt vmcnt(0)" ::: "memory");          \
        __builtin_amdgcn_s_barrier();                                             \
    } while (0)

    f32x4 acc[8][4] = {};
    s16x8 a0[8], b0[4], a1[8], b1[4];

    STAGE(0); STAGE(1); STAGE(2);
    asm volatile("s_waitcnt vmcnt(4)" ::: "memory");   // t0,t1 done; t2 in flight
    __builtin_amdgcn_s_barrier();
    {
        const char* bp_ = lds;
        RDA(a0, bp_, 0); RDA(a0, bp_, 1); RDA(a0, bp_, 2); RDA(a0, bp_, 3);
        RDA(a0, bp_, 4); RDA(a0, bp_, 5); RDA(a0, bp_, 6); RDA(a0, bp_, 7);
        RDB(b0, bp_, 0); RDB(b0, bp_, 1); RDB(b0, bp_, 2); RDB(b0, bp_, 3);
    }

    for (int tt = 0; tt < 15; ++tt) {
        STEP(2 * tt + 1, a1, b1, a0, b0);
        STEP(2 * tt + 2, a0, b0, a1, b1);
    }
    STEP(31, a1, b1, a0, b0);
    MM4(0, a1, b1); MM4(1, a1, b1); MM4(2, a1, b1); MM4(3, a1, b1);
    MM4(4, a1, b1); MM4(5, a1, b1); MM4(6, a1, b1); MM4(7, a1, b1);

#undef STAGE
#undef RDA
#undef RDB
#undef MM4
#undef STEP

    const float* bias = (nmat == 0) ? biasK : (nmat == 1) ? biasQ : biasV;
    u16* outKQ = (nmat == 0) ? Kb : Qb;
    const int colbase = ncol * 256 + wc * 64;
#pragma unroll
    for (int FM = 0; FM < 8; ++FM) {
#pragma unroll
        for (int fn = 0; fn < 4; ++fn) {
            const int col = colbase + fn * 16 + l15;
            const float bvv = bias[col];
            const int rbase = mt * 256 + wr * 128 + FM * 16 + (l16 << 2);
#pragma unroll
            for (int j = 0; j < 4; ++j) {
                const int row = rbase + j;
                const u16 hb = f2bf(acc[FM][fn][j] + bvv);
                if (nmat == 2) {
                    const int b = row >> 8, tt2 = row & 255;
                    Vt[(size_t)b * 262144 + (size_t)col * 256 + tt2] = hb;
                } else {
                    outKQ[(size_t)row * 1024 + col] = hb;
                }
            }
        }
    }
}

// ====== FUSED scores+softmax v2: 512 threads, full-row blocks ======
// grid = 128 batches x 2 row-halves (ti).  ti=0: rows 0-127 x cols 0-127;
// ti=1: rows 128-255 x cols 0-255.  8 waves (2M x 4N): per-wave 64 rows x
// 32 (ti=0) / 64 (ti=1) cols.  LDS stride 72 (pad +8) kills the 8-way
// 128B-stride bank conflict (reg-staged, so padding is legal).
// Softmax: in-reg scale+mask -> 16-lane shfl col-reduce -> cross-wave via
// redM/redS[4][128] -> P bf16 direct (masked cols -> exp(-inf)=0).
__global__ __launch_bounds__(512, 2) void scores_sm2(const u16* __restrict__ Qb,
                                                     const u16* __restrict__ Kb,
                                                     u16* __restrict__ P) {
    __shared__ u16 As[128 * 72];
    __shared__ u16 Bs[256 * 72];
    __shared__ float redM[4][128];
    __shared__ float redS[4][128];

    const int bid = blockIdx.x;
    const int b = bid >> 1, ti = bid & 1;
    const int nN = 2 << ti;                       // col frags per wave (2 or 4)
    const int nBrow = 128 << ti;                  // B rows staged (=cols)
    const u16* Ap = Qb + ((size_t)b * 256 + (size_t)ti * 128) * 1024;
    const u16* Bp = Kb + (size_t)b * 256 * 1024;

    const int tid  = threadIdx.x;
    const int lane = tid & 63;
    const int w    = tid >> 6;
    const int wr   = w >> 2, wc = w & 3;
    const int l15  = lane & 15, l16 = lane >> 4;
    const int sr   = tid >> 3;                    // 0..63
    const int sc   = (tid & 7) << 3;

    f32x4 acc[4][4] = {};

    for (int k0 = 0; k0 < 1024; k0 += 64) {
#pragma unroll
        for (int it = 0; it < 2; ++it) {
            const int r = it * 64 + sr;
            *reinterpret_cast<s16x8*>(&As[r * 72 + sc]) =
                *reinterpret_cast<const s16x8*>(&Ap[(size_t)r * 1024 + k0 + sc]);
        }
#pragma unroll
        for (int it = 0; it < 4; ++it) {
            if (it * 64 < nBrow) {
                const int r = it * 64 + sr;
                *reinterpret_cast<s16x8*>(&Bs[r * 72 + sc]) =
                    *reinterpret_cast<const s16x8*>(&Bp[(size_t)r * 1024 + k0 + sc]);
            }
        }
        __syncthreads();
#pragma unroll
        for (int kk = 0; kk < 64; kk += 32) {
            const int kcol = kk + l16 * 8;
            s16x8 a[4], bb[4];
#pragma unroll
            for (int m = 0; m < 4; ++m)
                a[m] = *reinterpret_cast<const s16x8*>(&As[(wr * 64 + m * 16 + l15) * 72 + kcol]);
#pragma unroll
            for (int n = 0; n < 4; ++n)
                if (n < nN)
                    bb[n] = *reinterpret_cast<const s16x8*>(&Bs[(wc * 16 * nN + n * 16 + l15) * 72 + kcol]);
#pragma unroll
            for (int m = 0; m < 4; ++m)
#pragma unroll
                for (int n = 0; n < 4; ++n)
                    if (n < nN)
                        MFMA(a[m], bb[n], acc[m][n]);
        }
        __syncthreads();
    }

    // ---- fused softmax over complete rows ----
    const int r0 = l16 << 2;
    const float scale = 0.03125f;
    const float NEG = -__builtin_inff();

#pragma unroll
    for (int m = 0; m < 4; ++m) {
#pragma unroll
        for (int j = 0; j < 4; ++j) {
            const int rr = wr * 64 + m * 16 + r0 + j;
            const int t_ = ti * 128 + rr;
            float mx = NEG;
#pragma unroll
            for (int n = 0; n < 4; ++n)
                if (n < nN) {
                    const int s_ = wc * 16 * nN + n * 16 + l15;
                    float v = acc[m][n][j] * scale;
                    v = (s_ <= t_) ? v : NEG;
                    acc[m][n][j] = v;
                    mx = fmaxf(mx, v);
                }
#pragma unroll
            for (int off = 1; off < 16; off <<= 1) mx = fmaxf(mx, __shfl_xor(mx, off, 64));
            if (l15 == 0) redM[wc][rr] = mx;
        }
    }
    __syncthreads();

#pragma unroll
    for (int m = 0; m < 4; ++m) {
#pragma unroll
        for (int j = 0; j < 4; ++j) {
            const int rr = wr * 64 + m * 16 + r0 + j;
            const float MX = fmaxf(fmaxf(redM[0][rr], redM[1][rr]),
                                   fmaxf(redM[2][rr], redM[3][rr]));
            float s = 0.f;
#pragma unroll
            for (int n = 0; n < 4; ++n)
                if (n < nN) {
                    float e = __expf(acc[m][n][j] - MX);
                    acc[m][n][j] = e;
                    s += e;
                }
#pragma unroll
            for (int off = 1; off < 16; off <<= 1) s += __shfl_xor(s, off, 64);
            if (l15 == 0) redS[wc][rr] = s;
        }
    }
    __syncthreads();

#pragma unroll
    for (int m = 0; m < 4; ++m) {
#pragma unroll
        for (int j = 0; j < 4; ++j) {
            const int rr = wr * 64 + m * 16 + r0 + j;
            const int t_ = ti * 128 + rr;
            const float inv = 1.0f / (redS[0][rr] + redS[1][rr] + redS[2][rr] + redS[3][rr]);
            u16* Pr = P + (size_t)b * 65536 + (size_t)t_ * 256;
#pragma unroll
            for (int n = 0; n < 4; ++n)
                if (n < nN) {
                    const int s_ = wc * 16 * nN + n * 16 + l15;
                    Pr[s_] = f2bf(acc[m][n][j] * inv);
                }
        }
    }
    // cols >= nBrow for ti=0 rows are never read by pv (kmax clip) -> no write needed
}

// ---------------- reg-staged 128x128 mainloop (pv), pad-72 ----------------
__device__ inline void gemm_mainloop(const u16* __restrict__ Ap, const u16* __restrict__ Bp,
                                     int lda, int ldb, int kLen,
                                     u16* As, u16* Bs, f32x4 (&acc)[4][4]) {
    const int tid  = threadIdx.x;
    const int lane = tid & 63;
    const int wr   = (tid >> 7) & 1;
    const int wc   = (tid >> 6) & 1;
    const int sr   = tid >> 3;
    const int sc   = (tid & 7) << 3;

    for (int k0 = 0; k0 < kLen; k0 += 64) {
#pragma unroll
        for (int it = 0; it < 4; ++it) {
            int r = it * 32 + sr;
            *reinterpret_cast<s16x8*>(&As[r * 72 + sc]) =
                *reinterpret_cast<const s16x8*>(&Ap[(size_t)r * lda + k0 + sc]);
            *reinterpret_cast<s16x8*>(&Bs[r * 72 + sc]) =
                *reinterpret_cast<const s16x8*>(&Bp[(size_t)r * ldb + k0 + sc]);
        }
        __syncthreads();
#pragma unroll
        for (int kk = 0; kk < 64; kk += 32) {
            const int kcol = kk + (lane >> 4) * 8;
            s16x8 a[4], bfr[4];
#pragma unroll
            for (int m = 0; m < 4; ++m)
                a[m] = *reinterpret_cast<const s16x8*>(&As[(wr * 64 + m * 16 + (lane & 15)) * 72 + kcol]);
#pragma unroll
            for (int n = 0; n < 4; ++n)
                bfr[n] = *reinterpret_cast<const s16x8*>(&Bs[(wc * 64 + n * 16 + (lane & 15)) * 72 + kcol]);
#pragma unroll
            for (int m = 0; m < 4; ++m)
#pragma unroll
                for (int n = 0; n < 4; ++n)
                    acc[m][n] = __builtin_amdgcn_mfma_f32_16x16x32_bf16(a[m], bfr[n], acc[m][n], 0, 0, 0);
        }
        __syncthreads();
    }
}

// ---------------- PV: out = P @ V  (Vt is [b][d][t] so NT) ----------------
__global__ __launch_bounds__(256) void pv_gemm(const u16* __restrict__ P, const u16* __restrict__ Vt,
                                               float* __restrict__ O) {
    __shared__ u16 As[128 * 72];
    __shared__ u16 Bs[128 * 72];
    const int bid = blockIdx.x;
    const int b   = bid >> 4;
    const int r   = bid & 15;
    const int mt  = r >> 3;
    const int ntl = r & 7;
    const u16* Ap = P + (size_t)b * 65536 + (size_t)mt * 128 * 256;
    const u16* Bp = Vt + (size_t)b * 262144 + (size_t)ntl * 128 * 256;
    const int kmax = (mt + 1) * 128;

    f32x4 acc[4][4] = {};
    gemm_mainloop(Ap, Bp, 256, 256, kmax, As, Bs, acc);

    const int tid  = threadIdx.x;
    const int lane = tid & 63;
    const int wr   = (tid >> 7) & 1;
    const int wc   = (tid >> 6) & 1;
    const int r0 = (lane >> 4) << 2;
    const int c0 = lane & 15;
#pragma unroll
    for (int m = 0; m < 4; ++m) {
#pragma unroll
        for (int n = 0; n < 4; ++n) {
            const int d = ntl * 128 + wc * 64 + n * 16 + c0;
#pragma unroll
            for (int j = 0; j < 4; ++j) {
                const int t = mt * 128 + wr * 64 + m * 16 + r0 + j;
                O[((size_t)b * 256 + t) * 1024 + d] = acc[m][n][j];
            }
        }
    }
}

// ---------------- launcher ----------------
extern "C" void kernel_launch(void* const* d_in, const int* in_sizes, int n_in,
                              void* d_out, int out_size, void* d_ws, size_t ws_size,
                              hipStream_t stream) {
    (void)in_sizes; (void)n_in; (void)out_size; (void)ws_size;
    const float* x  = (const float*)d_in[0];
    const float* Wk = (const float*)d_in[1];
    const float* bk = (const float*)d_in[2];
    const float* Wq = (const float*)d_in[3];
    const float* bq = (const float*)d_in[4];
    const float* Wv = (const float*)d_in[5];
    const float* bv = (const float*)d_in[6];
    float* out = (float*)d_out;
    char* ws = (char*)d_ws;

    // ws layout (bytes):
    //   [0,            67108864)  xb  bf16 x [32768][1024]  (dead after qkv)
    //   [33554432,     50331648)  P   bf16 [128][256][256]  (overlays dead xb half)
    //   [67108864,     73400320)  Wb  bf16 Wk|Wq|Wv
    //   [73400320,    140509184)  Kb ; [140509184, 207618048) Qb
    //   [207618048,   274726912)  Vt  bf16 values^T [128][1024][256]
    u16*   xb = (u16*)(ws + 0);
    u16*   Wb = (u16*)(ws + 67108864);
    u16*   Kb = (u16*)(ws + 73400320);
    u16*   Qb = (u16*)(ws + 140509184);
    u16*   Vt = (u16*)(ws + 207618048);
    u16*   P  = (u16*)(ws + 33554432);

    cvt_f32_bf16<<<2048, 256, 0, stream>>>(x, xb, 33554432 / 4);
    cvt_f32_bf16<<<512, 256, 0, stream>>>(Wk, Wb, 1048576 / 4);
    cvt_f32_bf16<<<512, 256, 0, stream>>>(Wq, Wb + 1048576, 1048576 / 4);
    cvt_f32_bf16<<<512, 256, 0, stream>>>(Wv, Wb + 2097152, 1048576 / 4);
    qkv256<<<1536, 512, 131072, stream>>>(xb, Wb, bk, bq, bv, Kb, Qb, Vt);
    scores_sm2<<<256, 512, 0, stream>>>(Qb, Kb, P);
    pv_gemm<<<2048, 256, 0, stream>>>(P, Vt, out);
}